// Round 6
// baseline (3329.722 us; speedup 1.0000x reference)
//
#include <hip/hip_runtime.h>

// GRU decoder with Bahdanau attention, B=32, T=64, O=E=384, H=768.
// Persistent cooperative kernel, 3 grid barriers per step (monotonic 2-level).
// Weights f32 in LDS (one-time load). 8-row aligned type-pure store units.

#define DEVI static __device__ __forceinline__
typedef float f32x4 __attribute__((ext_vector_type(4)));
typedef unsigned u32x4 __attribute__((ext_vector_type(4)));
typedef unsigned u32x2 __attribute__((ext_vector_type(2)));
typedef unsigned short ushort_t;

constexpr int ATTN_OFF = 786432;

// f32 ws offsets
constexpr int OFF_HALL  = 0;        // 65 x (768k,32b) h, rotated
constexpr int OFF_U     = 1597440;  // (b,k) 32*768 uncached
constexpr int OFF_WALL  = 1622016;  // 64 x (b,o) w_i, rotated
constexpr int OFF_HISTF = 2408448;  // 64 x (b,o) f32 outputs, rotated
constexpr int OFF_GH    = 3194880;  // (row,b) 2304*32 uncached
constexpr int OFF_GIE   = 3268608;  // (row,b) 2304*32 uncached
constexpr int OFF_FE    = 3342336;  // (row,b) 384*32 uncached
constexpr int OFF_GE    = 3354624;  // (row,b) 768*32 uncached
constexpr int OFF_FP    = 3379200;  // (row,b) 384*32 uncached
constexpr int OFF_CP    = 3391488;  // (row,b) 768*32 uncached
constexpr int OFF_GHM   = 3416064;  // Gh (768,768) f32
constexpr int OFF_GWM   = 4005888;  // Gw (768,384) f32
constexpr int OFF_GEM   = 4300800;  // Ge (768,384) f32
constexpr int OFF_GB    = 4595712;  // 768
constexpr int OFF_V1    = 4596480;  // M = sum|v|
constexpr int OFF_BAR   = 4596512;  // 1152 u32 (monotonic counters)
constexpr int OFF_F32END= 4597664;
// ushort offsets into w16 = (ushort*)(ws + OFF_F32END)
constexpr int O16_CALL = 0;         // 64 x (b,k) bf16 c_t, rotated
constexpr int O16_HIST = 1572864;   // 64 x (b,o) bf16 hist_t, rotated

DEVI float fast_tanh(float x) {
  float a = __builtin_fabsf(x);
  float e = __expf(-2.0f * a);
  float r = __fdividef(1.0f - e, 1.0f + e);
  return __builtin_copysignf(r, x);
}
DEVI float sigmoidf_(float x) { return __fdividef(1.0f, 1.0f + __expf(-x)); }
DEVI float bflo(unsigned u) { return __uint_as_float(u << 16); }
DEVI float bfhi(unsigned u) { return __uint_as_float(u & 0xffff0000u); }
DEVI unsigned f2bf(float f) {
  unsigned u = __float_as_uint(f);
  return (u + 0x7fffu + ((u >> 16) & 1u)) >> 16;
}

DEVI float nc_ld_f1(const float* p) {
  float r;
  asm volatile("global_load_dword %0, %1, off sc0 sc1\n\ts_waitcnt vmcnt(0)"
               : "=&v"(r) : "v"(p) : "memory");
  return r;
}
DEVI f32x4 nc_ld4(const float* p) {
  f32x4 r;
  asm volatile("global_load_dwordx4 %0, %1, off sc0 sc1\n\ts_waitcnt vmcnt(0)"
               : "=&v"(r) : "v"(p) : "memory");
  return r;
}
DEVI void nc_ld4x2(const float* p0, const float* p1, f32x4& r0, f32x4& r1) {
  asm volatile(
      "global_load_dwordx4 %0, %2, off sc0 sc1\n\t"
      "global_load_dwordx4 %1, %3, off sc0 sc1\n\t"
      "s_waitcnt vmcnt(0)"
      : "=&v"(r0), "=&v"(r1) : "v"(p0), "v"(p1) : "memory");
}
DEVI void nc_st4(float* p, f32x4 v) {
  asm volatile("global_store_dwordx4 %0, %1, off sc0 sc1" :: "v"(p), "v"(v) : "memory");
}
DEVI void nc_st4u(ushort_t* p, u32x4 v) {
  asm volatile("global_store_dwordx4 %0, %1, off sc0 sc1" :: "v"(p), "v"(v) : "memory");
}

// monotonic 2-level grid barrier: no resets, poll super >= 32*k
DEVI void gridbar(unsigned* bar, unsigned k) {
  asm volatile("s_waitcnt vmcnt(0)" ::: "memory");
  __syncthreads();
  if (threadIdx.x == 0) {
    unsigned* grpc = bar + ((blockIdx.x >> 3) << 4);  // 32 groups, 64B apart
    unsigned* super = bar + 512;
    unsigned a = __hip_atomic_fetch_add(grpc, 1u, __ATOMIC_RELAXED, __HIP_MEMORY_SCOPE_AGENT);
    if (a == 8u * k - 1u)
      __hip_atomic_fetch_add(super, 1u, __ATOMIC_RELAXED, __HIP_MEMORY_SCOPE_AGENT);
    while (__hip_atomic_load(super, __ATOMIC_RELAXED, __HIP_MEMORY_SCOPE_AGENT) < 32u * k)
      __builtin_amdgcn_s_sleep(1);
  }
  __syncthreads();
}

// ---------- precompute Gh/Gw/Ge (f32) + gb ----------
__global__ __launch_bounds__(256) void kprepG(const float* __restrict__ attn_W,
                                              const float* __restrict__ fcW,
                                              const float* __restrict__ fcb,
                                              float* __restrict__ ws) {
  int bid = blockIdx.x, tid = threadIdx.x;
  if (bid < 288) {
    int rt = bid / 6, kt = bid % 6;
    int r0 = rt * 16;
    int kg = kt * 256 + tid;
    float acc[16];
#pragma unroll
    for (int q = 0; q < 16; ++q) acc[q] = 0.f;
    for (int o = 0; o < 384; ++o) {
      float f = fcW[o * 1536 + kg];
#pragma unroll
      for (int q = 0; q < 16; ++q)
        acc[q] = fmaf(attn_W[(r0 + q) * 1152 + 768 + o], f, acc[q]);
    }
#pragma unroll
    for (int q = 0; q < 16; ++q) {
      int r = r0 + q;
      if (kg < 768)       ws[OFF_GHM + r * 768 + kg] = acc[q];
      else if (kg < 1152) ws[OFF_GWM + r * 384 + (kg - 768)] = acc[q];
      else                ws[OFF_GEM + r * 384 + (kg - 1152)] = acc[q];
    }
  } else {
    for (int r = tid; r < 768; r += 256) {
      float a = 0.f;
      for (int o = 0; o < 384; ++o) a = fmaf(attn_W[r * 1152 + 768 + o], fcb[o], a);
      ws[OFF_GB + r] = a;
    }
  }
}

// ---------- prep: h transpose, zeros, M, barrier ----------
__global__ __launch_bounds__(256) void kprep0(const float* __restrict__ hidden,
                                              const float* __restrict__ vW,
                                              float* __restrict__ ws) {
  ushort_t* w16 = (ushort_t*)(ws + OFF_F32END);
  int bid = blockIdx.x, tid = threadIdx.x;
  int gtid = bid * 256 + tid;
  if (gtid < 24576) {
    int k = gtid >> 5, b = gtid & 31;
    ws[OFF_HALL + gtid] = hidden[b * 768 + k];
  } else if (gtid < 36864) {
    ((unsigned*)(w16 + O16_CALL))[gtid - 24576] = 0u;
  } else if (gtid < 43008) {
    ((unsigned*)(w16 + O16_HIST))[gtid - 36864] = 0u;
  }
  if (gtid < 1152) ((unsigned*)(ws + OFF_BAR))[gtid] = 0u;
  if (bid == 0) {
    __shared__ float vred[256];
    float a = 0.f;
    for (int k = tid; k < 768; k += 256) a += __builtin_fabsf(vW[k]);
    vred[tid] = a;
    __syncthreads();
    for (int s2 = 128; s2 > 0; s2 >>= 1) {
      if (tid < s2) vred[tid] += vred[tid + s2];
      __syncthreads();
    }
    if (tid == 0) ws[OFF_V1] = vred[0];
  }
}

// ---------- main persistent cooperative kernel ----------
__global__ void __launch_bounds__(1024, 4)
kmain(const int* __restrict__ target, const float* __restrict__ emb,
      const float* __restrict__ attn_W, const float* __restrict__ attn_b,
      const float* __restrict__ vW,
      const float* __restrict__ Wih, const float* __restrict__ Whh,
      const float* __restrict__ bih, const float* __restrict__ bhh,
      const float* __restrict__ fcW, const float* __restrict__ fcb,
      float* __restrict__ outp, float* __restrict__ ws) {
  const int bid = blockIdx.x, tid = threadIdx.x;
  const int wv = tid >> 6, lane = tid & 63;
  const int b32 = lane & 31, kh = lane >> 5;
  const int vb = ((bid & 7) << 5) | (bid >> 3);  // XCD-major
  const int xcd = vb >> 5, slot = vb & 31;
  unsigned* bar = (unsigned*)(ws + OFF_BAR);
  ushort_t* w16 = (ushort_t*)(ws + OFF_F32END);

  // LDS: persistent weights + small phase workspace (132 KB total)
  __shared__ __align__(16) float sW_A[24 * 768];   // 73.7 KB
  __shared__ __align__(16) float sW_B[16 * 384];   // 24.6 KB
  __shared__ __align__(16) float sW_C[14 * 384];   // 21.5 KB
  __shared__ __align__(16) float sUn[3072];        // 12 KB

  // row partitions: A in aligned 8-row units (528 units)
  const int ubA = (vb * 528) >> 8, ueA = ((vb + 1) * 528) >> 8;
  const int rbA = ubA * 8, nA = (ueA - ubA) * 8;   // 16 or 24
  const int lb  = xcd * 28 + (slot - 4);
  const int rbB = (slot >= 4) ? (lb * 3456) / 224 : 0;
  const int reB = (slot >= 4) ? ((lb + 1) * 3456) / 224 : 0;
  const int nB  = reB - rbB;
  const int rbC = xcd * 144 + ((slot * 144) >> 5);
  const int reC = xcd * 144 + (((slot + 1) * 144) >> 5);

  // ---- one-time LDS weight loads (x4, parallel) ----
  for (int q = tid; q < nA * 192; q += 1024) {
    int lr = q / 192, col = (q - lr * 192) * 4;
    int row = rbA + lr;
    const float* src;
    if (row < 768)       src = attn_W + row * 1152;
    else if (row < 3072) src = Whh + (row - 768) * 768;
    else if (row < 3840) src = ws + OFF_GHM + (row - 3072) * 768;
    else                 src = fcW + (row - 3840) * 1536;
    *(f32x4*)&sW_A[lr * 768 + col] = *(const f32x4*)(src + col);
  }
  if (slot >= 4) {
    for (int q = tid; q < nB * 96; q += 1024) {
      int lr = q / 96, col = (q - lr * 96) * 4;
      int row = rbB + lr;
      const float* src;
      if (row < 2304)      src = Wih + row * 768;
      else if (row < 2688) src = fcW + (row - 2304) * 1536 + 1152;
      else                 src = ws + OFF_GEM + (row - 2688) * 384;
      *(f32x4*)&sW_B[lr * 384 + col] = *(const f32x4*)(src + col);
    }
  }
  for (int q = tid; q < 14 * 96; q += 1024) {
    int lr = q / 96, col = (q - lr * 96) * 4;
    const float* src = nullptr;
    if (lr < 9) {
      int grow = vb * 3 + (lr / 3) + (lr % 3) * 768;
      src = Wih + grow * 768 + 384;
    } else {
      int r = rbC + (lr - 9);
      if (r < reC) src = (r < 384) ? fcW + r * 1536 + 768
                                   : ws + OFF_GWM + (r - 384) * 384;
    }
    if (src) *(f32x4*)&sW_C[lr * 384 + col] = *(const f32x4*)(src + col);
  }
  __syncthreads();

  const float Mv = ws[OFF_V1];
  const int ks = wv & 7, rg = wv >> 3;
  const int k0 = ks * 96 + kh * 48;
  unsigned bk = 0;

  for (int i = 0; i < 64; ++i) {
    // ======== Phase A: u, gh, c_i, out_{i-1} (aligned 8-row units, K=768) ====
    {
      float* part_ = sUn;          // 2048
      float* stage = sUn + 2048;   // 256
      float* pf    = sUn + 2304;   // 768 (24 rows x 32)
      // prefetch CP/FP once
      if (i > 0 && tid < 192) {
        int rr = tid >> 3, bq = tid & 7;
        int row = rbA + rr;
        if (rr < nA && row >= 3072) {
          const float* src = row < 3840 ? ws + OFF_CP + (row - 3072) * 32 + bq * 4
                                        : ws + OFF_FP + (row - 3840) * 32 + bq * 4;
          *(f32x4*)&pf[rr * 32 + bq * 4] = nc_ld4(src);
        }
      }
      // h slice into registers (cached, coalesced)
      float xr[48];
      const float* hb = ws + OFF_HALL + i * 24576 + b32;
#pragma unroll
      for (int q = 0; q < 48; ++q) xr[q] = hb[(k0 + q) * 32];

      const int nsw = nA >> 3;
      for (int sw = 0; sw < nsw; ++sw) {
        const int lr0 = sw * 8 + rg * 4;
        const int row0u = rbA + sw * 8;
        const bool skip = (i == 0 && rbA + lr0 >= 3072);
        float a[4];
#pragma unroll
        for (int r = 0; r < 4; ++r) {
          float acc = 0.f;
          if (!skip) {
            const float* wp = &sW_A[(lr0 + r) * 768 + k0];
#pragma unroll
            for (int q = 0; q < 12; ++q) {
              f32x4 w = *(const f32x4*)(wp + q * 4);
              acc = fmaf(w[0], xr[q * 4 + 0], acc);
              acc = fmaf(w[1], xr[q * 4 + 1], acc);
              acc = fmaf(w[2], xr[q * 4 + 2], acc);
              acc = fmaf(w[3], xr[q * 4 + 3], acc);
            }
          }
          a[r] = acc;
        }
#pragma unroll
        for (int r = 0; r < 4; ++r) a[r] += __shfl_xor(a[r], 32);
        if (kh == 0) {
#pragma unroll
          for (int r = 0; r < 4; ++r)
            part_[ks * 256 + (rg * 4 + r) * 32 + b32] = a[r];
        }
        __syncthreads();
        if (tid < 256) {
          int r8 = tid >> 5, bb = tid & 31;
          float sum = 0.f;
#pragma unroll
          for (int kv = 0; kv < 8; ++kv) sum += part_[kv * 256 + tid];
          int row = row0u + r8;
          if (row < 768) sum += attn_b[row];
          else if (row < 3072) sum += bhh[row - 768];
          else if (i > 0) sum += pf[(sw * 8 + r8) * 32 + bb];
          stage[r8 * 32 + bb] = sum;
        }
        __syncthreads();
        // stores: unit is type-pure and 8-aligned
        if (row0u < 768) {
          if (tid < 64) {
            int b = tid & 31, h4 = tid >> 5;
            f32x4 v;
#pragma unroll
            for (int e = 0; e < 4; ++e) v[e] = stage[(h4 * 4 + e) * 32 + b];
            nc_st4(ws + OFF_U + b * 768 + row0u + h4 * 4, v);
          }
        } else if (row0u < 3072) {
          if (tid < 64) {
            int rr8 = tid >> 3, bq = tid & 7;
            nc_st4(ws + OFF_GH + (row0u - 768 + rr8) * 32 + bq * 4,
                   *(f32x4*)&stage[rr8 * 32 + bq * 4]);
          }
        } else if (row0u < 3840) {
          if (i > 0 && tid < 32) {
            u32x4 pk;
#pragma unroll
            for (int j = 0; j < 4; ++j)
              pk[j] = f2bf(stage[(2 * j) * 32 + tid]) |
                      (f2bf(stage[(2 * j + 1) * 32 + tid]) << 16);
            nc_st4u(w16 + O16_CALL + i * 24576 + tid * 768 + (row0u - 3072), pk);
          }
        } else {
          if (i > 0) {
            if (tid < 32) {
              u32x4 pk;
#pragma unroll
              for (int j = 0; j < 4; ++j)
                pk[j] = f2bf(stage[(2 * j) * 32 + tid]) |
                        (f2bf(stage[(2 * j + 1) * 32 + tid]) << 16);
              nc_st4u(w16 + O16_HIST + i * 12288 + tid * 384 + (row0u - 3840), pk);
            } else if (tid < 96) {
              int b = tid & 31, h4 = (tid >> 5) - 1;
              f32x4 v;
#pragma unroll
              for (int e = 0; e < 4; ++e) v[e] = stage[(h4 * 4 + e) * 32 + b];
              nc_st4(ws + OFF_HISTF + i * 12288 + b * 384 + (row0u - 3840) + h4 * 4, v);
            }
          }
        }
        __syncthreads();
      }
    }
    gridbar(bar, ++bk);

    // ======== Phase B: attention (32 blocks) | gie/fe/ge GEMM (224 blocks) ====
    if (slot < 4) {
      const int bb = xcd * 4 + slot;
      float* u_s   = sUn;           // 768
      float* p_l   = sUn + 768;     // 64
      float* d_l   = sUn + 832;     // 16 (pad)
      float* wred2 = sUn + 848;     // 1536 (4 x 384)
      float* wfin  = sUn + 2384;    // 384
      if (tid < 192) *(f32x4*)&u_s[tid * 4] = nc_ld4(ws + OFF_U + bb * 768 + tid * 4);
      __syncthreads();
      // scores: wave wv handles t in {wv, wv+16, wv+32, wv+48}
      {
        const int klo = lane * 12;
        f32x4 u0 = *(const f32x4*)&u_s[klo];
        f32x4 u1 = *(const f32x4*)&u_s[klo + 4];
        f32x4 u2 = *(const f32x4*)&u_s[klo + 8];
        f32x4 v0 = *(const f32x4*)(vW + klo);
        f32x4 v1 = *(const f32x4*)(vW + klo + 4);
        f32x4 v2 = *(const f32x4*)(vW + klo + 8);
#pragma unroll
        for (int c4 = 0; c4 < 4; ++c4) {
          int t = wv + c4 * 16;
          float s = 0.f;
          if (t <= i) {
            const ushort_t* cp = w16 + O16_CALL + t * 24576 + bb * 768 + klo;
            u32x2 ca = *(const u32x2*)cp;
            u32x2 cbm = *(const u32x2*)(cp + 4);
            u32x2 cc = *(const u32x2*)(cp + 8);
            s = fmaf(fast_tanh(u0[0] + bflo(ca[0])), v0[0], s);
            s = fmaf(fast_tanh(u0[1] + bfhi(ca[0])), v0[1], s);
            s = fmaf(fast_tanh(u0[2] + bflo(ca[1])), v0[2], s);
            s = fmaf(fast_tanh(u0[3] + bfhi(ca[1])), v0[3], s);
            s = fmaf(fast_tanh(u1[0] + bflo(cbm[0])), v1[0], s);
            s = fmaf(fast_tanh(u1[1] + bfhi(cbm[0])), v1[1], s);
            s = fmaf(fast_tanh(u1[2] + bflo(cbm[1])), v1[2], s);
            s = fmaf(fast_tanh(u1[3] + bfhi(cbm[1])), v1[3], s);
            s = fmaf(fast_tanh(u2[0] + bflo(cc[0])), v2[0], s);
            s = fmaf(fast_tanh(u2[1] + bfhi(cc[0])), v2[1], s);
            s = fmaf(fast_tanh(u2[2] + bflo(cc[1])), v2[2], s);
            s = fmaf(fast_tanh(u2[3] + bfhi(cc[1])), v2[3], s);
          }
#pragma unroll
          for (int d = 1; d < 64; d <<= 1) s += __shfl_xor(s, d);
          if (lane == 0) p_l[t] = (t <= i) ? __expf(s - Mv) : 0.f;
        }
      }
      __syncthreads();
      // denominator (wave 15) || weighted-hist partials (threads < 768)
      if (wv == 15) {
        float pv = p_l[lane];
#pragma unroll
        for (int d = 1; d < 64; d <<= 1) pv += __shfl_xor(pv, d);
        if (lane == 0) d_l[0] = __fdividef(1.0f, pv);
      }
      if (tid < 768) {
        int opair = tid % 192, tpar = tid / 192;
        int o0 = opair * 2;
        float a0 = 0.f, a1 = 0.f;
        for (int t = tpar; t <= i; t += 4) {
          unsigned hv = *(const unsigned*)(w16 + O16_HIST + t * 12288 + bb * 384 + o0);
          float p = p_l[t];
          a0 = fmaf(p, bflo(hv), a0);
          a1 = fmaf(p, bfhi(hv), a1);
        }
        wred2[tpar * 384 + o0] = a0;
        wred2[tpar * 384 + o0 + 1] = a1;
      }
      __syncthreads();
      if (tid < 384) {
        float s = wred2[tid] + wred2[384 + tid] + wred2[768 + tid] + wred2[1152 + tid];
        wfin[tid] = s * d_l[0];
      } else if (tid >= 768 && tid < 832) {
        int t = tid - 768;
        if (t <= i)
          outp[ATTN_OFF + bb * 2080 + (i * (i + 1)) / 2 + t] = p_l[t] * d_l[0];
      }
      __syncthreads();
      if (tid < 96)
        nc_st4(ws + OFF_WALL + i * 12288 + bb * 384 + tid * 4, *(f32x4*)&wfin[tid * 4]);
    } else {
      float* part_  = sUn;          // 2048
      float* stageB = sUn + 2048;   // 512
      const int gl = wv >> 2, kq = wv & 3;
      const int tok = target[b32 * 65 + i];
      const int koff = kq * 96 + kh * 48;
      const float* xe = emb + tok * 384 + koff;
      f32x4 x_[12];
#pragma unroll
      for (int q = 0; q < 12; ++q) x_[q] = *(const f32x4*)(xe + q * 4);
      float a[4];
#pragma unroll
      for (int r = 0; r < 4; ++r) {
        int lr = gl * 4 + r;
        float acc = 0.f;
        if (lr < nB) {
          const float* wp = &sW_B[lr * 384 + koff];
#pragma unroll
          for (int q = 0; q < 12; ++q) {
            f32x4 w = *(const f32x4*)(wp + q * 4);
            acc = fmaf(w[0], x_[q][0], acc);
            acc = fmaf(w[1], x_[q][1], acc);
            acc = fmaf(w[2], x_[q][2], acc);
            acc = fmaf(w[3], x_[q][3], acc);
          }
        }
        a[r] = acc;
      }
#pragma unroll
      for (int r = 0; r < 4; ++r) a[r] += __shfl_xor(a[r], 32);
      if (kh == 0) {
#pragma unroll
        for (int r = 0; r < 4; ++r)
          part_[((gl * 4 + r) * 4 + kq) * 32 + b32] = a[r];
      }
      __syncthreads();
      if (tid < 512) {
        int glr = tid >> 5, bb = tid & 31;
        if (glr < nB) {
          float sum = part_[(glr * 4 + 0) * 32 + bb] + part_[(glr * 4 + 1) * 32 + bb]
                    + part_[(glr * 4 + 2) * 32 + bb] + part_[(glr * 4 + 3) * 32 + bb];
          int row = rbB + glr;
          if (row < 2304) sum += bih[row];
          else if (row < 2688) sum += fcb[row - 2304];
          else sum += ws[OFF_GB + (row - 2688)];
          stageB[glr * 32 + bb] = sum;
        }
      }
      __syncthreads();
      if (tid < 128) {
        int r16 = tid >> 3, bq = tid & 7;
        if (r16 < nB) {
          int row = rbB + r16;
          f32x4 v = *(f32x4*)&stageB[r16 * 32 + bq * 4];
          float* dst;
          if (row < 2304) dst = ws + OFF_GIE + row * 32 + bq * 4;
          else if (row < 2688) dst = ws + OFF_FE + (row - 2304) * 32 + bq * 4;
          else dst = ws + OFF_GE + (row - 2688) * 32 + bq * 4;
          nc_st4(dst, v);
        }
      }
      __syncthreads();
    }
    gridbar(bar, ++bk);

    // ======== Phase C: giw, fpart/cpart, gates (w read cached from WALL) ====
    {
      float* g_lds   = sUn;          // 576
      float* giw_lds = sUn + 576;    // 288
      float* fpst    = sUn + 864;    // 160
      float* gat     = sUn + 1024;   // 96
      const float* wsrc = ws + OFF_WALL + i * 12288;  // cached
      if (wv < 9) {
        const float* wp = &sW_C[wv * 384 + kh * 192];
        const float* xp = wsrc + b32 * 384 + kh * 192;
        float acc = 0.f;
#pragma unroll 8
        for (int q = 0; q < 48; ++q) {
          f32x4 w = *(const f32x4*)(wp + q * 4);
          f32x4 x = *(const f32x4*)(xp + q * 4);
          acc = fmaf(w[0], x[0], acc); acc = fmaf(w[1], x[1], acc);
          acc = fmaf(w[2], x[2], acc); acc = fmaf(w[3], x[3], acc);
        }
        acc += __shfl_xor(acc, 32);
        if (kh == 0) giw_lds[wv * 32 + b32] = acc;
      } else if (wv < 14) {
        int rl = wv - 9, r = rbC + rl;
        if (r < reC) {
          const float* wp = &sW_C[(9 + rl) * 384 + kh * 192];
          const float* xp = wsrc + b32 * 384 + kh * 192;
          float acc = 0.f;
#pragma unroll 8
          for (int q = 0; q < 48; ++q) {
            f32x4 w = *(const f32x4*)(wp + q * 4);
            f32x4 x = *(const f32x4*)(xp + q * 4);
            acc = fmaf(w[0], x[0], acc); acc = fmaf(w[1], x[1], acc);
            acc = fmaf(w[2], x[2], acc); acc = fmaf(w[3], x[3], acc);
          }
          acc += __shfl_xor(acc, 32);
          if (kh == 0) fpst[rl * 32 + b32] = acc;
        }
      } else {
        int t2 = tid - 896;
        if (t2 < 72) {
          int q0 = t2 * 2, q1 = q0 + 1;
          const float* pa;
          const float* pb;
          {
            int row = q0 >> 3, bq = q0 & 7;
            int rr2 = row < 9 ? row : row - 9;
            int r = vb * 3 + (rr2 % 3) + (rr2 / 3) * 768;
            pa = ws + (row < 9 ? OFF_GIE : OFF_GH) + r * 32 + bq * 4;
          }
          {
            int row = q1 >> 3, bq = q1 & 7;
            int rr2 = row < 9 ? row : row - 9;
            int r = vb * 3 + (rr2 % 3) + (rr2 / 3) * 768;
            pb = ws + (row < 9 ? OFF_GIE : OFF_GH) + r * 32 + bq * 4;
          }
          f32x4 v0, v1;
          nc_ld4x2(pa, pb, v0, v1);
          *(f32x4*)&g_lds[q0 * 4] = v0;
          *(f32x4*)&g_lds[q1 * 4] = v1;
        }
      }
      __syncthreads();
      if (tid < 96) {
        int jl = tid >> 5, bb = tid & 31;
        int j = vb * 3 + jl;
        float gi_r = g_lds[jl * 32 + bb];
        float gi_z = g_lds[(3 + jl) * 32 + bb];
        float gi_n = g_lds[(6 + jl) * 32 + bb];
        float gh_r = g_lds[(9 + jl) * 32 + bb];
        float gh_z = g_lds[(12 + jl) * 32 + bb];
        float gh_n = g_lds[(15 + jl) * 32 + bb];
        float giw_r = giw_lds[(jl * 3 + 0) * 32 + bb];
        float giw_z = giw_lds[(jl * 3 + 1) * 32 + bb];
        float giw_n = giw_lds[(jl * 3 + 2) * 32 + bb];
        float hold = ws[OFF_HALL + i * 24576 + j * 32 + bb];
        float r_ = sigmoidf_(gi_r + giw_r + gh_r);
        float z_ = sigmoidf_(gi_z + giw_z + gh_z);
        float n_ = fast_tanh(fmaf(r_, gh_n, gi_n + giw_n));
        gat[jl * 32 + bb] = (1.0f - z_) * n_ + z_ * hold;
      } else if (tid < 136) {
        int t2 = tid - 96, rl = t2 >> 3, bq = t2 & 7;
        int r = rbC + rl;
        if (r < reC) {
          const float* addp = r < 384 ? ws + OFF_FE + r * 32 + bq * 4
                                      : ws + OFF_GE + (r - 384) * 32 + bq * 4;
          f32x4 ad = nc_ld4(addp);
          f32x4 v;
#pragma unroll
          for (int e = 0; e < 4; ++e) v[e] = fpst[rl * 32 + bq * 4 + e] + ad[e];
          float* dst = r < 384 ? ws + OFF_FP + r * 32 + bq * 4
                               : ws + OFF_CP + (r - 384) * 32 + bq * 4;
          nc_st4(dst, v);
        }
      }
      __syncthreads();
      if (tid < 24) {
        int jl3 = tid >> 3, bq = tid & 7;
        f32x4 v = *(f32x4*)&gat[jl3 * 32 + bq * 4];
        nc_st4(ws + OFF_HALL + (i + 1) * 24576 + (vb * 3 + jl3) * 32 + bq * 4, v);
      }
    }
    gridbar(bar, ++bk);
  }

  // ======== epilogue: out_63 = F_h h_64 + fp_63 ====
  if (slot < 3) {
    int o = xcd * 48 + slot * 16 + wv;
    const float* hcol = ws + OFF_HALL + 64 * 24576 + b32;
    const float* wrow = fcW + o * 1536 + kh * 384;
    float acc = 0.f;
#pragma unroll 4
    for (int q = 0; q < 96; ++q) {
      f32x4 wq = *(const f32x4*)(wrow + q * 4);
      int k = kh * 384 + q * 4;
      acc = fmaf(wq[0], hcol[k * 32], acc);
      acc = fmaf(wq[1], hcol[(k + 1) * 32], acc);
      acc = fmaf(wq[2], hcol[(k + 2) * 32], acc);
      acc = fmaf(wq[3], hcol[(k + 3) * 32], acc);
    }
    acc += __shfl_xor(acc, 32);
    if (kh == 0) {
      float fp = nc_ld_f1(ws + OFF_FP + o * 32 + b32);
      outp[b32 * 24576 + o * 64 + 63] = acc + fp;
    }
  }
  // ======== final transpose: outputs[b][o][t], t=0..62 from HISTF ====
  if (tid < 48) {
    int pair = vb * 48 + tid;
    int b = pair / 384, o = pair - b * 384;
    const float* src = ws + OFF_HISTF + b * 384 + o;
    float* dst = outp + b * 24576 + o * 64;
#pragma unroll 7
    for (int t = 0; t < 63; ++t) dst[t] = src[(t + 1) * 12288];
  }
}

extern "C" void kernel_launch(void* const* d_in, const int* in_sizes, int n_in,
                              void* d_out, int out_size, void* d_ws, size_t ws_size,
                              hipStream_t stream) {
  const int*   target = (const int*)d_in[0];
  const float* hidden = (const float*)d_in[1];
  // d_in[2] = teacher_forcing_ratio (== 1, deterministic path)
  const float* emb    = (const float*)d_in[3];
  const float* attn_W = (const float*)d_in[4];
  const float* attn_b = (const float*)d_in[5];
  const float* vW     = (const float*)d_in[6];
  const float* Wih    = (const float*)d_in[7];
  const float* Whh    = (const float*)d_in[8];
  const float* bih    = (const float*)d_in[9];
  const float* bhh    = (const float*)d_in[10];
  const float* fcW    = (const float*)d_in[11];
  const float* fcb    = (const float*)d_in[12];
  float* outp = (float*)d_out;
  float* ws   = (float*)d_ws;

  kprepG<<<289, 256, 0, stream>>>(attn_W, fcW, fcb, ws);
  kprep0<<<256, 256, 0, stream>>>(hidden, vW, ws);

  void* args[] = {(void*)&target, (void*)&emb, (void*)&attn_W, (void*)&attn_b,
                  (void*)&vW, (void*)&Wih, (void*)&Whh, (void*)&bih, (void*)&bhh,
                  (void*)&fcW, (void*)&fcb, (void*)&outp, (void*)&ws};
  hipLaunchCooperativeKernel((const void*)kmain, dim3(256), dim3(1024), args, 0, stream);
}